// Round 1
// baseline (1098.336 us; speedup 1.0000x reference)
//
#include <hip/hip_runtime.h>

using f32x4 = __attribute__((ext_vector_type(4))) float;
using u16x8 = __attribute__((ext_vector_type(8))) unsigned short;
using u16x4 = __attribute__((ext_vector_type(4))) unsigned short;

#define HD   1024
#define BB   256
#define SS   128
#define VOCN 5292
#define VOCP 5376

// ---------- ws layout (bytes, 256-aligned) ----------
static constexpr size_t OFF_W1H  = 0;                      // 1024*1024 bf16
static constexpr size_t OFF_W1E  = 2097152;                // 1024*2048 bf16
static constexpr size_t OFF_WG   = 6291456;                // 4096*3072 bf16
static constexpr size_t OFF_OUTW = 31457280;               // 5376*1024 bf16
static constexpr size_t OFF_HID  = 42467328;               // 256*1024 bf16
static constexpr size_t OFF_XCAT = 42991616;               // 256*3072 bf16
static constexpr size_t OFF_HB   = 44564480;               // 256*1024 f32
static constexpr size_t OFF_EN   = 45613056;               // 32768 f32
static constexpr size_t OFF_GATE = 45744128;               // 256*4096 f32
static constexpr size_t OFF_HBF  = 49938432;               // 256*1024 bf16
static constexpr size_t OFF_LOG  = 50462720;               // 256*5376 f32
static constexpr size_t OFF_CNT  = 55967744;               // 4 B counter
static constexpr size_t OFF_ENC  = 55968000;               // 32768*2048 bf16 (optional)
static constexpr size_t NEED_ENC = OFF_ENC + 134217728ull;

__device__ __forceinline__ unsigned short f2bf(float x) {
    unsigned u = __builtin_bit_cast(unsigned, x);
    unsigned r = (u + 0x7FFFu + ((u >> 16) & 1u)) >> 16;
    return (unsigned short)r;
}
__device__ __forceinline__ float bf2f(unsigned short h) {
    unsigned u = ((unsigned)h) << 16;
    return __builtin_bit_cast(float, u);
}
__device__ __forceinline__ float fast_tanh(float x) {
    return 1.f - 2.f / (__expf(2.f * x) + 1.f);
}
__device__ __forceinline__ float sigm(float x) { return 1.f / (1.f + __expf(-x)); }

__device__ __forceinline__ void mfma16(f32x4& d, u16x8 a, u16x8 b) {
    asm("v_mfma_f32_16x16x32_bf16 %0, %1, %2, %0" : "+v"(d) : "v"(a), "v"(b));
}

// ---------------- conversion kernels ----------------
__global__ void k_conv_attn1(const float* __restrict__ w,
                             unsigned short* __restrict__ w1h,
                             unsigned short* __restrict__ w1e) {
    const int col = blockIdx.x * 256 + threadIdx.x;   // < 3072
    const int row = blockIdx.y;                       // < 1024
    const float v = w[(size_t)row * 3072 + col];
    const unsigned short h = f2bf(v);
    if (col < 1024) w1h[(size_t)row * 1024 + col] = h;
    else            w1e[(size_t)row * 2048 + (col - 1024)] = h;
}

__global__ void k_conv_wg(const float* __restrict__ wih, const float* __restrict__ whh,
                          unsigned short* __restrict__ wg) {
    const int k = blockIdx.x * 256 + threadIdx.x;     // < 3072
    const int u = blockIdx.y;                         // < 4096
    float v = wih[(size_t)u * 3072 + k];
    if (k < 1024) v += whh[(size_t)u * 1024 + k];     // hidden feeds both w_ih and w_hh
    wg[(size_t)u * 3072 + k] = f2bf(v);
}

__global__ void k_conv_outw(const float* __restrict__ ow, unsigned short* __restrict__ owb) {
    const int c = blockIdx.x * 256 + threadIdx.x;     // < 1024
    const int r = blockIdx.y;                         // < 5376
    owb[(size_t)r * 1024 + c] = (r < VOCN) ? f2bf(ow[(size_t)r * 1024 + c]) : (unsigned short)0;
}

__global__ void k_f2bf(const float* __restrict__ x, unsigned short* __restrict__ y, int n) {
    const int i = blockIdx.x * 256 + threadIdx.x;
    if (i < n) y[i] = f2bf(x[i]);
}

__global__ void k_conv_enc(const float* __restrict__ x, unsigned short* __restrict__ y) {
    const size_t i = ((size_t)blockIdx.x * 256 + threadIdx.x) * 4;
    const float4 v = *(const float4*)(x + i);
    u16x4 o; o[0] = f2bf(v.x); o[1] = f2bf(v.y); o[2] = f2bf(v.z); o[3] = f2bf(v.w);
    *(u16x4*)(y + i) = o;
}

// mask dtype sniffing: count nonzero bytes in first 32768 bytes
__global__ void k_maskcnt(const unsigned char* __restrict__ m, unsigned int* __restrict__ cnt) {
    const int i = blockIdx.x * 256 + threadIdx.x;     // 128 blocks -> 32768
    const unsigned long long bal = __ballot(m[i] != 0);
    if ((threadIdx.x & 63) == 0) atomicAdd(cnt, (unsigned)__popcll(bal));
}

__global__ void k_einit(float* __restrict__ e, const float* __restrict__ b2) {
    e[blockIdx.x * 256 + threadIdx.x] = b2[0];
}

// ---------------- GEMM: C[M,N] = A[M,K] @ Bt[N,K]^T (bf16 MFMA) ----------------
// EPI 0: store C ; EPI 1: store C + bias[col] ; EPI 2: fused attention-energy epilogue
template <int EPI, bool AF32, bool SWZ>
__global__ __launch_bounds__(256) void k_gemm(const void* __restrict__ Ap,
                                              const unsigned short* __restrict__ Bt,
                                              float* __restrict__ C,
                                              int M, int N, int K,
                                              const float* __restrict__ bias,
                                              const float* __restrict__ hb,
                                              const float* __restrict__ w2,
                                              float* __restrict__ energ) {
    __shared__ unsigned short As[128 * 64];
    __shared__ unsigned short Bs[128 * 64];
    const int nbn = N >> 7;
    int bm, bn;
    if (SWZ) {  // group same-bm N-tiles on one XCD (requires (M>>7)%8==0, nbn grid-exact)
        const int bid = blockIdx.x;
        const int xcd = bid & 7;
        const int idx = bid >> 3;
        const int per = (M >> 7) >> 3;
        bm = xcd * per + idx / nbn;
        bn = idx % nbn;
    } else {
        bm = blockIdx.x / nbn;
        bn = blockIdx.x % nbn;
    }
    const int t = threadIdx.x;
    const int lane = t & 63;
    const int w = t >> 6;
    const int lg = lane >> 4, lr = lane & 15;
    const int wr = w >> 1, wc = w & 1;

    f32x4 acc[4][4] = {};

    const int srow = t >> 3;          // 0..31
    const int scol = (t & 7) << 3;    // 0,8,...,56

    for (int k0 = 0; k0 < K; k0 += 64) {
#pragma unroll
        for (int i = 0; i < 4; ++i) {
            const int r = i * 32 + srow;
            const size_t boff = (size_t)(bn * 128 + r) * K + k0 + scol;
            *(u16x8*)&Bs[r * 64 + scol] = *(const u16x8*)(Bt + boff);
            const size_t aoff = (size_t)(bm * 128 + r) * K + k0 + scol;
            if (AF32) {
                const float* af = (const float*)Ap + aoff;
                const float4 v0 = *(const float4*)af;
                const float4 v1 = *(const float4*)(af + 4);
                u16x8 h;
                h[0] = f2bf(v0.x); h[1] = f2bf(v0.y); h[2] = f2bf(v0.z); h[3] = f2bf(v0.w);
                h[4] = f2bf(v1.x); h[5] = f2bf(v1.y); h[6] = f2bf(v1.z); h[7] = f2bf(v1.w);
                *(u16x8*)&As[r * 64 + scol] = h;
            } else {
                *(u16x8*)&As[r * 64 + scol] =
                    *(const u16x8*)((const unsigned short*)Ap + aoff);
            }
        }
        __syncthreads();
#pragma unroll
        for (int kk = 0; kk < 64; kk += 32) {
            u16x8 a[4], b[4];
#pragma unroll
            for (int i = 0; i < 4; ++i)
                a[i] = *(const u16x8*)&As[(wr * 64 + i * 16 + lr) * 64 + kk + lg * 8];
#pragma unroll
            for (int i = 0; i < 4; ++i)
                b[i] = *(const u16x8*)&Bs[(wc * 64 + i * 16 + lr) * 64 + kk + lg * 8];
#pragma unroll
            for (int i = 0; i < 4; ++i)
#pragma unroll
                for (int j = 0; j < 4; ++j) mfma16(acc[i][j], a[i], b[j]);
        }
        __syncthreads();
    }
    // MFMA->VALU hazard fence (inline-asm MFMA: compiler won't insert wait states)
    asm volatile("s_nop 7\ns_nop 7\ns_nop 7"
                 : "+v"(acc[0][0]), "+v"(acc[0][1]), "+v"(acc[0][2]), "+v"(acc[0][3]),
                   "+v"(acc[1][0]), "+v"(acc[1][1]), "+v"(acc[1][2]), "+v"(acc[1][3]));
    asm volatile("s_nop 7\ns_nop 7\ns_nop 7"
                 : "+v"(acc[2][0]), "+v"(acc[2][1]), "+v"(acc[2][2]), "+v"(acc[2][3]),
                   "+v"(acc[3][0]), "+v"(acc[3][1]), "+v"(acc[3][2]), "+v"(acc[3][3]));

    if constexpr (EPI == 2) {
        // energies[row] += sum_j tanh(acc + hb[b][j]) * w2[j]
#pragma unroll
        for (int i = 0; i < 4; ++i) {
#pragma unroll
            for (int r = 0; r < 4; ++r) {
                const int row = bm * 128 + wr * 64 + i * 16 + lg * 4 + r;
                const int b = row & (BB - 1);
                float part = 0.f;
#pragma unroll
                for (int j = 0; j < 4; ++j) {
                    const int col = bn * 128 + wc * 64 + j * 16 + lr;
                    const float v = acc[i][j][r] + hb[b * HD + col];
                    part += fast_tanh(v) * w2[col];
                }
                part += __shfl_xor(part, 8, 16);
                part += __shfl_xor(part, 4, 16);
                part += __shfl_xor(part, 2, 16);
                part += __shfl_xor(part, 1, 16);
                if (lr == 0) atomicAdd(&energ[row], part);
            }
        }
    } else {
#pragma unroll
        for (int i = 0; i < 4; ++i) {
            const int row0 = bm * 128 + wr * 64 + i * 16 + lg * 4;
#pragma unroll
            for (int j = 0; j < 4; ++j) {
                const int col = bn * 128 + wc * 64 + j * 16 + lr;
                const float bv = (EPI == 1) ? bias[col] : 0.f;
#pragma unroll
                for (int r = 0; r < 4; ++r)
                    C[(size_t)(row0 + r) * N + col] = acc[i][j][r] + bv;
            }
        }
    }
}

// ---------------- masked softmax over S ----------------
__global__ void k_softmax(float* __restrict__ e, const void* __restrict__ mask,
                          const unsigned int* __restrict__ cnt) {
    const int b = blockIdx.x;
    const int s = threadIdx.x;  // 128
    const int lane = s & 63, wv = s >> 6;
    float v = e[s * BB + b];
    bool mk;
    if (*cnt > 4096u) mk = ((const unsigned char*)mask)[s * BB + b] != 0;   // uint8 storage
    else              mk = ((const int*)mask)[s * BB + b] != 0;             // int32/float32
    if (mk) v = -__builtin_inff();
    float m = v;
#pragma unroll
    for (int o = 32; o; o >>= 1) m = fmaxf(m, __shfl_xor(m, o, 64));
    __shared__ float sm[2], ssum[2];
    if (lane == 0) sm[wv] = m;
    __syncthreads();
    m = fmaxf(sm[0], sm[1]);
    const float ex = __expf(v - m);
    float su = ex;
#pragma unroll
    for (int o = 32; o; o >>= 1) su += __shfl_xor(su, o, 64);
    if (lane == 0) ssum[wv] = su;
    __syncthreads();
    su = ssum[0] + ssum[1];
    e[s * BB + b] = ex / su;
}

// ---------------- context + xcat build ----------------
template <bool BF>
__global__ void k_ctx(const void* __restrict__ encp, const float* __restrict__ wts,
                      const float* __restrict__ hidden, unsigned short* __restrict__ xcat) {
    const int b = blockIdx.x >> 1, half = blockIdx.x & 1, t = threadIdx.x;
    __shared__ float wl[SS];
    if (t < SS) wl[t] = wts[t * BB + b];
    __syncthreads();
    if (half == 0)
        for (int i = t; i < HD; i += 256) xcat[(size_t)b * 3072 + i] = f2bf(hidden[b * HD + i]);
    const int d0 = half * 1024 + t * 4;
    float a0 = 0, a1 = 0, a2 = 0, a3 = 0;
    for (int s = 0; s < SS; ++s) {
        const float wg = wl[s];
        const size_t base = ((size_t)(s * BB + b)) * 2048 + d0;
        if (BF) {
            const u16x4 v = *(const u16x4*)((const unsigned short*)encp + base);
            a0 += wg * bf2f(v[0]); a1 += wg * bf2f(v[1]);
            a2 += wg * bf2f(v[2]); a3 += wg * bf2f(v[3]);
        } else {
            const float4 v = *(const float4*)((const float*)encp + base);
            a0 += wg * v.x; a1 += wg * v.y; a2 += wg * v.z; a3 += wg * v.w;
        }
    }
    u16x4 o; o[0] = f2bf(a0); o[1] = f2bf(a1); o[2] = f2bf(a2); o[3] = f2bf(a3);
    *(u16x4*)(xcat + (size_t)b * 3072 + 1024 + d0) = o;
}

// ---------------- LSTM elementwise ----------------
__global__ void k_lstm(const float* __restrict__ gates, const float* __restrict__ bih,
                       const float* __restrict__ bhh, const float* __restrict__ cell,
                       float* __restrict__ hout, float* __restrict__ cout,
                       unsigned short* __restrict__ hbf) {
    const int idx = blockIdx.x * 256 + threadIdx.x;  // < 262144
    const int b = idx >> 10, j = idx & 1023;
    const size_t g0 = (size_t)b * 4096;
    const float gi = gates[g0 + j]        + bih[j]        + bhh[j];
    const float gf = gates[g0 + 1024 + j] + bih[1024 + j] + bhh[1024 + j];
    const float gg = gates[g0 + 2048 + j] + bih[2048 + j] + bhh[2048 + j];
    const float go = gates[g0 + 3072 + j] + bih[3072 + j] + bhh[3072 + j];
    const float c = sigm(gf) * cell[idx] + sigm(gi) * fast_tanh(gg);
    const float h = sigm(go) * fast_tanh(c);
    hout[idx] = h;
    cout[idx] = c;
    hbf[idx] = f2bf(h);
}

// ---------------- log-softmax over VOC ----------------
__global__ __launch_bounds__(256) void k_logsoftmax(const float* __restrict__ logits,
                                                    const float* __restrict__ ob,
                                                    float* __restrict__ out) {
    const int b = blockIdx.x, t = threadIdx.x, lane = t & 63, wv = t >> 6;
    __shared__ float red[4];
    const float* row = logits + (size_t)b * VOCP;
    float mx = -3.4e38f;
    for (int j = t; j < VOCN; j += 256) mx = fmaxf(mx, row[j] + ob[j]);
#pragma unroll
    for (int o = 32; o; o >>= 1) mx = fmaxf(mx, __shfl_xor(mx, o, 64));
    if (lane == 0) red[wv] = mx;
    __syncthreads();
    mx = fmaxf(fmaxf(red[0], red[1]), fmaxf(red[2], red[3]));
    __syncthreads();
    float su = 0.f;
    for (int j = t; j < VOCN; j += 256) su += __expf(row[j] + ob[j] - mx);
#pragma unroll
    for (int o = 32; o; o >>= 1) su += __shfl_xor(su, o, 64);
    if (lane == 0) red[wv] = su;
    __syncthreads();
    su = red[0] + red[1] + red[2] + red[3];
    const float lse = mx + logf(su);
    for (int j = t; j < VOCN; j += 256) out[(size_t)b * VOCN + j] = row[j] + ob[j] - lse;
}

// ---------------- launch ----------------
extern "C" void kernel_launch(void* const* d_in, const int* in_sizes, int n_in,
                              void* d_out, int out_size, void* d_ws, size_t ws_size,
                              hipStream_t stream) {
    (void)in_sizes; (void)n_in; (void)out_size;
    const float* hidden = (const float*)d_in[0];
    const float* cell   = (const float*)d_in[1];
    const float* enc    = (const float*)d_in[2];
    const void*  mask   = d_in[3];
    const float* a1w    = (const float*)d_in[4];
    const float* a1b    = (const float*)d_in[5];
    const float* a2w    = (const float*)d_in[6];
    const float* a2b    = (const float*)d_in[7];
    const float* wih    = (const float*)d_in[8];
    const float* whh    = (const float*)d_in[9];
    const float* bih    = (const float*)d_in[10];
    const float* bhh    = (const float*)d_in[11];
    const float* outw   = (const float*)d_in[12];
    const float* outb   = (const float*)d_in[13];

    char* ws = (char*)d_ws;
    unsigned short* w1h   = (unsigned short*)(ws + OFF_W1H);
    unsigned short* w1e   = (unsigned short*)(ws + OFF_W1E);
    unsigned short* wg    = (unsigned short*)(ws + OFF_WG);
    unsigned short* owb   = (unsigned short*)(ws + OFF_OUTW);
    unsigned short* hidbf = (unsigned short*)(ws + OFF_HID);
    unsigned short* xcat  = (unsigned short*)(ws + OFF_XCAT);
    float*          hb    = (float*)(ws + OFF_HB);
    float*          energ = (float*)(ws + OFF_EN);
    float*          gates = (float*)(ws + OFF_GATE);
    unsigned short* hbf   = (unsigned short*)(ws + OFF_HBF);
    float*          logits= (float*)(ws + OFF_LOG);
    unsigned int*   cnt   = (unsigned int*)(ws + OFF_CNT);
    unsigned short* encb  = (unsigned short*)(ws + OFF_ENC);

    float* out  = (float*)d_out;
    float* hout = out + (size_t)BB * VOCN;
    float* cout = hout + (size_t)BB * HD;

    const bool use_enc_bf = ws_size >= NEED_ENC;

    hipMemsetAsync(ws + OFF_CNT, 0, 4, stream);
    k_maskcnt<<<128, 256, 0, stream>>>((const unsigned char*)mask, cnt);
    k_conv_attn1<<<dim3(12, 1024), 256, 0, stream>>>(a1w, w1h, w1e);
    k_conv_wg<<<dim3(12, 4096), 256, 0, stream>>>(wih, whh, wg);
    k_conv_outw<<<dim3(4, VOCP), 256, 0, stream>>>(outw, owb);
    k_f2bf<<<1024, 256, 0, stream>>>(hidden, hidbf, BB * HD);
    if (use_enc_bf) k_conv_enc<<<65536, 256, 0, stream>>>(enc, encb);

    // hid_proj + attn1_b -> hb  [256,1024]
    k_gemm<1, false, false><<<16, 256, 0, stream>>>(hidbf, w1h, hb, 256, 1024, 1024,
                                                    a1b, nullptr, nullptr, nullptr);
    k_einit<<<128, 256, 0, stream>>>(energ, a2b);
    // enc_proj GEMM with fused tanh/att2/atomic-reduce epilogue
    if (use_enc_bf)
        k_gemm<2, false, true><<<2048, 256, 0, stream>>>(encb, w1e, nullptr, 32768, 1024, 2048,
                                                         nullptr, hb, a2w, energ);
    else
        k_gemm<2, true, true><<<2048, 256, 0, stream>>>(enc, w1e, nullptr, 32768, 1024, 2048,
                                                        nullptr, hb, a2w, energ);
    k_softmax<<<BB, SS, 0, stream>>>(energ, mask, cnt);
    if (use_enc_bf) k_ctx<true><<<512, 256, 0, stream>>>(encb, energ, hidden, xcat);
    else            k_ctx<false><<<512, 256, 0, stream>>>(enc, energ, hidden, xcat);
    // gates = xcat @ wg^T  [256,4096]
    k_gemm<0, false, false><<<64, 256, 0, stream>>>(xcat, wg, gates, 256, 4096, 3072,
                                                    nullptr, nullptr, nullptr, nullptr);
    k_lstm<<<1024, 256, 0, stream>>>(gates, bih, bhh, cell, hout, cout, hbf);
    // logits = h_new @ out_w^T  [256,5376(pad)]
    k_gemm<0, false, false><<<84, 256, 0, stream>>>(hbf, owb, logits, 256, VOCP, 1024,
                                                    nullptr, nullptr, nullptr, nullptr);
    k_logsoftmax<<<BB, 256, 0, stream>>>(logits, outb, out);
}

// Round 3
// 742.476 us; speedup vs baseline: 1.4793x; 1.4793x over previous
//
#include <hip/hip_runtime.h>

using f32x4 = __attribute__((ext_vector_type(4))) float;
using u16x8 = __attribute__((ext_vector_type(8))) unsigned short;
using u16x4 = __attribute__((ext_vector_type(4))) unsigned short;

#define HD   1024
#define BB   256
#define SS   128
#define VOCN 5292
#define VOCP 5376

// ---------- ws layout (bytes, 256-aligned) ----------
static constexpr size_t OFF_W1H  = 0;                      // 1024*1024 bf16   (2 MB)
static constexpr size_t OFF_W1E  = 2097152;                // 1024*2048 bf16   (4 MB)
static constexpr size_t OFF_WG   = 6291456;                // 4096*3072 bf16   (24 MB)
static constexpr size_t OFF_OUTW = 31457280;               // 5376*1024 bf16   (10.5 MB)
static constexpr size_t OFF_HID  = 42467328;               // 256*1024 bf16
static constexpr size_t OFF_XCAT = 42991616;               // 256*3072 bf16
static constexpr size_t OFF_HB   = 44564480;               // 256*1024 f32 (raw hid_proj)
static constexpr size_t OFF_EN   = 45613056;               // 32768 f32
static constexpr size_t OFF_GATE = 45744128;               // 2 x 256*4096 f32 (split-K partials)
static constexpr size_t OFF_HBF  = 54132736;               // 256*1024 bf16
static constexpr size_t OFF_LOG  = 54657024;               // 2 x 256*5376 f32 (split-K partials)
static constexpr size_t OFF_CNT  = 65667072;               // 4 B counter
static constexpr size_t OFF_CTX  = 65667328;               // 4 x 256*2048 f32 (ctx partials)
static constexpr size_t OFF_ENC  = 74055936;               // 32768*2048 bf16
static constexpr size_t NEED_ENC = OFF_ENC + 134217728ull;

__device__ __forceinline__ unsigned short f2bf(float x) {
    unsigned u = __builtin_bit_cast(unsigned, x);
    unsigned r = (u + 0x7FFFu + ((u >> 16) & 1u)) >> 16;
    return (unsigned short)r;
}
__device__ __forceinline__ float bf2f(unsigned short h) {
    unsigned u = ((unsigned)h) << 16;
    return __builtin_bit_cast(float, u);
}
__device__ __forceinline__ float fast_tanh(float x) {
    return 1.f - 2.f / (__expf(2.f * x) + 1.f);
}
__device__ __forceinline__ float sigm(float x) { return 1.f / (1.f + __expf(-x)); }

__device__ __forceinline__ void mfma16(f32x4& d, u16x8 a, u16x8 b) {
    asm("v_mfma_f32_16x16x32_bf16 %0, %1, %2, %0" : "+v"(d) : "v"(a), "v"(b));
}

__device__ __forceinline__ void gload16(const void* g, void* l) {
    __builtin_amdgcn_global_load_lds(
        (const __attribute__((address_space(1))) void*)g,
        (__attribute__((address_space(3))) void*)l, 16, 0, 0);
}

__device__ __forceinline__ u16x8 cvt8(const float* __restrict__ p) {
    const float4 v0 = *(const float4*)p;
    const float4 v1 = *(const float4*)(p + 4);
    u16x8 h;
    h[0] = f2bf(v0.x); h[1] = f2bf(v0.y); h[2] = f2bf(v0.z); h[3] = f2bf(v0.w);
    h[4] = f2bf(v1.x); h[5] = f2bf(v1.y); h[6] = f2bf(v1.z); h[7] = f2bf(v1.w);
    return h;
}

// ---------------- conversion kernels (8 elem/thread, u16x8 stores) ----------------
__global__ void k_conv_attn1(const float* __restrict__ w,
                             unsigned short* __restrict__ w1h,
                             unsigned short* __restrict__ w1e) {
    const int idx = blockIdx.x * 256 + threadIdx.x;   // 1024*384
    const int row = idx / 384, p = idx - row * 384;
    const int col0 = p * 8;
    const u16x8 h = cvt8(w + (size_t)row * 3072 + col0);
    if (col0 < 1024) *(u16x8*)&w1h[(size_t)row * 1024 + col0] = h;
    else             *(u16x8*)&w1e[(size_t)row * 2048 + (col0 - 1024)] = h;
}

__global__ void k_conv_wg(const float* __restrict__ wih, const float* __restrict__ whh,
                          unsigned short* __restrict__ wg) {
    const int idx = blockIdx.x * 256 + threadIdx.x;   // 4096*384
    const int row = idx / 384, p = idx - row * 384;
    const int col0 = p * 8;
    const float* src = wih + (size_t)row * 3072 + col0;
    float v[8];
#pragma unroll
    for (int i = 0; i < 8; ++i) v[i] = src[i];
    if (col0 < 1024) {
        const float* s2 = whh + (size_t)row * 1024 + col0;
#pragma unroll
        for (int i = 0; i < 8; ++i) v[i] += s2[i];
    }
    u16x8 h;
#pragma unroll
    for (int i = 0; i < 8; ++i) h[i] = f2bf(v[i]);
    *(u16x8*)&wg[(size_t)row * 3072 + col0] = h;
}

__global__ void k_conv_outw(const float* __restrict__ ow, unsigned short* __restrict__ owb) {
    const int idx = blockIdx.x * 256 + threadIdx.x;   // 5376*128
    const int r = idx >> 7, c0 = (idx & 127) << 3;
    u16x8 h = {};
    if (r < VOCN) h = cvt8(ow + (size_t)r * 1024 + c0);
    *(u16x8*)&owb[(size_t)r * 1024 + c0] = h;
}

__global__ void k_f2bf(const float* __restrict__ x, unsigned short* __restrict__ y, int n) {
    const int i = (blockIdx.x * 256 + threadIdx.x) * 8;
    if (i < n) *(u16x8*)&y[i] = cvt8(x + i);
}

__global__ void k_conv_enc(const float* __restrict__ x, unsigned short* __restrict__ y) {
    const size_t i = ((size_t)blockIdx.x * 256 + threadIdx.x) * 8;
    *(u16x8*)(y + i) = cvt8(x + i);
}

// mask dtype sniffing: count nonzero bytes in first 32768 bytes
__global__ void k_maskcnt(const unsigned char* __restrict__ m, unsigned int* __restrict__ cnt) {
    const int i = blockIdx.x * 256 + threadIdx.x;
    const unsigned long long bal = __ballot(m[i] != 0);
    if ((threadIdx.x & 63) == 0) atomicAdd(cnt, (unsigned)__popcll(bal));
}

__global__ void k_einit(float* __restrict__ e, const float* __restrict__ b2) {
    e[blockIdx.x * 256 + threadIdx.x] = b2[0];
}

// ---------------- GEMM: C[M,N] = A[M,K] @ Bt[N,K]^T (bf16 MFMA) ----------------
// global_load_lds(16B) staging, linear LDS dest, XOR-preswizzled global source,
// swizzled ds_read (conflict-free).  EPI 0: store C ; 2: fused attn-energy epilogue.
// PART: split-K -> C += blockIdx.y * M * N, k-range = [y*klen, (y+1)*klen)
template <int EPI, bool SWZ, bool PART>
__global__ __launch_bounds__(256) void k_gemm(const unsigned short* __restrict__ A,
                                              const unsigned short* __restrict__ Bt,
                                              float* __restrict__ C,
                                              int M, int N, int K, int klen,
                                              const float* __restrict__ hb,
                                              const float* __restrict__ a1b,
                                              const float* __restrict__ w2,
                                              float* __restrict__ energ) {
    __shared__ unsigned short As[128 * 64];
    __shared__ unsigned short Bs[128 * 64];
    const int nbn = N >> 7;
    int bm, bn;
    if (SWZ) {  // group same-bm N-tiles on one XCD ((M>>7)%8==0, grid exact)
        const int bid = blockIdx.x;
        const int xcd = bid & 7;
        const int idx = bid >> 3;
        const int per = (M >> 7) >> 3;
        bm = xcd * per + idx / nbn;
        bn = idx % nbn;
    } else {
        bm = blockIdx.x / nbn;
        bn = blockIdx.x % nbn;
    }
    if (PART) C += (size_t)blockIdx.y * M * N;
    const int kb = PART ? blockIdx.y * klen : 0;
    const int ke = kb + klen;

    const int t = threadIdx.x;
    const int lane = t & 63;
    const int w = t >> 6;
    const int lg = lane >> 4, lr = lane & 15;
    const int wr = w >> 1, wc = w & 1;
    // staging geometry: one gload16 per lane covers 16B; wave covers 8 rows x 128B
    const int r3 = lane >> 3;            // row within 8-row stripe
    const int c8 = lane & 7;             // 16B chunk within row
    const int csw = (c8 ^ r3) << 3;      // pre-swizzled source column (elements)
    const int sA = lr & 7;               // row&7 for read-side XOR

    f32x4 acc[4][4] = {};

    for (int k0 = kb; k0 < ke; k0 += 64) {
#pragma unroll
        for (int i = 0; i < 4; ++i) {
            const int rr = i * 32 + w * 8;
            gload16(A  + (size_t)(bm * 128 + rr + r3) * K + k0 + csw, &As[rr * 64]);
            gload16(Bt + (size_t)(bn * 128 + rr + r3) * K + k0 + csw, &Bs[rr * 64]);
        }
        asm volatile("s_waitcnt vmcnt(0)" ::: "memory");
        __syncthreads();
#pragma unroll
        for (int kk = 0; kk < 64; kk += 32) {
            const int cb = (kk >> 3) | lg;            // chunk 0..7
            const int co = ((cb ^ sA) << 3);          // swizzled element offset
            u16x8 a[4], b[4];
#pragma unroll
            for (int i = 0; i < 4; ++i)
                a[i] = *(const u16x8*)&As[(wr * 64 + i * 16 + lr) * 64 + co];
#pragma unroll
            for (int i = 0; i < 4; ++i)
                b[i] = *(const u16x8*)&Bs[(wc * 64 + i * 16 + lr) * 64 + co];
#pragma unroll
            for (int i = 0; i < 4; ++i)
#pragma unroll
                for (int j = 0; j < 4; ++j) mfma16(acc[i][j], a[i], b[j]);
        }
        __syncthreads();
    }
    // MFMA->VALU hazard fence (inline-asm MFMA: compiler won't insert wait states)
    asm volatile("s_nop 7\ns_nop 7\ns_nop 7"
                 : "+v"(acc[0][0]), "+v"(acc[0][1]), "+v"(acc[0][2]), "+v"(acc[0][3]),
                   "+v"(acc[1][0]), "+v"(acc[1][1]), "+v"(acc[1][2]), "+v"(acc[1][3]));
    asm volatile("s_nop 7\ns_nop 7\ns_nop 7"
                 : "+v"(acc[2][0]), "+v"(acc[2][1]), "+v"(acc[2][2]), "+v"(acc[2][3]),
                   "+v"(acc[3][0]), "+v"(acc[3][1]), "+v"(acc[3][2]), "+v"(acc[3][3]));

    if constexpr (EPI == 2) {
        // energies[row] += sum_j tanh(acc + hid_proj + a1b) * w2[j]
#pragma unroll
        for (int i = 0; i < 4; ++i) {
#pragma unroll
            for (int r = 0; r < 4; ++r) {
                const int row = bm * 128 + wr * 64 + i * 16 + lg * 4 + r;
                const int b = row & (BB - 1);
                float part = 0.f;
#pragma unroll
                for (int j = 0; j < 4; ++j) {
                    const int col = bn * 128 + wc * 64 + j * 16 + lr;
                    const float v = acc[i][j][r] + hb[b * HD + col] + a1b[col];
                    part += fast_tanh(v) * w2[col];
                }
                part += __shfl_xor(part, 8, 16);
                part += __shfl_xor(part, 4, 16);
                part += __shfl_xor(part, 2, 16);
                part += __shfl_xor(part, 1, 16);
                if (lr == 0) atomicAdd(&energ[row], part);
            }
        }
    } else {
#pragma unroll
        for (int i = 0; i < 4; ++i) {
            const int row0 = bm * 128 + wr * 64 + i * 16 + lg * 4;
#pragma unroll
            for (int j = 0; j < 4; ++j) {
                const int col = bn * 128 + wc * 64 + j * 16 + lr;
#pragma unroll
                for (int r = 0; r < 4; ++r)
                    C[(size_t)(row0 + r) * N + col] = acc[i][j][r];
            }
        }
    }
}

// f32-A fallback for the big energy GEMM (reg-staged; used only if ws too small for encb)
__global__ __launch_bounds__(256) void k_gemm_f32e(const float* __restrict__ A,
                                                   const unsigned short* __restrict__ Bt,
                                                   int M, int N, int K,
                                                   const float* __restrict__ hb,
                                                   const float* __restrict__ a1b,
                                                   const float* __restrict__ w2,
                                                   float* __restrict__ energ) {
    __shared__ unsigned short As[128 * 64];
    __shared__ unsigned short Bs[128 * 64];
    const int nbn = N >> 7;
    const int bid = blockIdx.x;
    const int xcd = bid & 7, idx = bid >> 3, per = (M >> 7) >> 3;
    const int bm = xcd * per + idx / nbn;
    const int bn = idx % nbn;
    const int t = threadIdx.x, lane = t & 63, w = t >> 6;
    const int lg = lane >> 4, lr = lane & 15;
    const int wr = w >> 1, wc = w & 1;
    f32x4 acc[4][4] = {};
    const int srow = t >> 3, scol = (t & 7) << 3;
    for (int k0 = 0; k0 < K; k0 += 64) {
#pragma unroll
        for (int i = 0; i < 4; ++i) {
            const int r = i * 32 + srow;
            *(u16x8*)&Bs[r * 64 + scol] = *(const u16x8*)(Bt + (size_t)(bn * 128 + r) * K + k0 + scol);
            *(u16x8*)&As[r * 64 + scol] = cvt8(A + (size_t)(bm * 128 + r) * K + k0 + scol);
        }
        __syncthreads();
#pragma unroll
        for (int kk = 0; kk < 64; kk += 32) {
            u16x8 a[4], b[4];
#pragma unroll
            for (int i = 0; i < 4; ++i) a[i] = *(const u16x8*)&As[(wr * 64 + i * 16 + lr) * 64 + kk + lg * 8];
#pragma unroll
            for (int i = 0; i < 4; ++i) b[i] = *(const u16x8*)&Bs[(wc * 64 + i * 16 + lr) * 64 + kk + lg * 8];
#pragma unroll
            for (int i = 0; i < 4; ++i)
#pragma unroll
                for (int j = 0; j < 4; ++j) mfma16(acc[i][j], a[i], b[j]);
        }
        __syncthreads();
    }
    asm volatile("s_nop 7\ns_nop 7\ns_nop 7"
                 : "+v"(acc[0][0]), "+v"(acc[0][1]), "+v"(acc[0][2]), "+v"(acc[0][3]),
                   "+v"(acc[1][0]), "+v"(acc[1][1]), "+v"(acc[1][2]), "+v"(acc[1][3]));
    asm volatile("s_nop 7\ns_nop 7\ns_nop 7"
                 : "+v"(acc[2][0]), "+v"(acc[2][1]), "+v"(acc[2][2]), "+v"(acc[2][3]),
                   "+v"(acc[3][0]), "+v"(acc[3][1]), "+v"(acc[3][2]), "+v"(acc[3][3]));
#pragma unroll
    for (int i = 0; i < 4; ++i) {
#pragma unroll
        for (int r = 0; r < 4; ++r) {
            const int row = bm * 128 + wr * 64 + i * 16 + lg * 4 + r;
            const int b = row & (BB - 1);
            float part = 0.f;
#pragma unroll
            for (int j = 0; j < 4; ++j) {
                const int col = bn * 128 + wc * 64 + j * 16 + lr;
                const float v = acc[i][j][r] + hb[b * HD + col] + a1b[col];
                part += fast_tanh(v) * w2[col];
            }
            part += __shfl_xor(part, 8, 16);
            part += __shfl_xor(part, 4, 16);
            part += __shfl_xor(part, 2, 16);
            part += __shfl_xor(part, 1, 16);
            if (lr == 0) atomicAdd(&energ[row], part);
        }
    }
}

// ---------------- masked softmax over S ----------------
__global__ void k_softmax(float* __restrict__ e, const void* __restrict__ mask,
                          const unsigned int* __restrict__ cnt) {
    const int b = blockIdx.x;
    const int s = threadIdx.x;  // 128
    const int lane = s & 63, wv = s >> 6;
    float v = e[s * BB + b];
    bool mk;
    if (*cnt > 4096u) mk = ((const unsigned char*)mask)[s * BB + b] != 0;   // uint8 storage
    else              mk = ((const int*)mask)[s * BB + b] != 0;             // int32/float32
    if (mk) v = -__builtin_inff();
    float m = v;
#pragma unroll
    for (int o = 32; o; o >>= 1) m = fmaxf(m, __shfl_xor(m, o, 64));
    __shared__ float sm[2], ssum[2];
    if (lane == 0) sm[wv] = m;
    __syncthreads();
    m = fmaxf(sm[0], sm[1]);
    const float ex = __expf(v - m);
    float su = ex;
#pragma unroll
    for (int o = 32; o; o >>= 1) su += __shfl_xor(su, o, 64);
    if (lane == 0) ssum[wv] = su;
    __syncthreads();
    su = ssum[0] + ssum[1];
    e[s * BB + b] = ex / su;
}

// ---------------- context einsum partials (grid: b x half x 4 s-chunks) ----------------
template <bool BF>
__global__ void k_ctx(const void* __restrict__ encp, const float* __restrict__ wts,
                      float* __restrict__ ctxp) {
    const int b = blockIdx.x, half = blockIdx.y, sc = blockIdx.z, t = threadIdx.x;
    const int d0 = half * 1024 + t * 4;
    const int s0 = sc * 32;
    __shared__ float wl[32];
    if (t < 32) wl[t] = wts[(s0 + t) * BB + b];
    __syncthreads();
    float a0 = 0, a1 = 0, a2 = 0, a3 = 0;
#pragma unroll 4
    for (int s = 0; s < 32; ++s) {
        const float wg = wl[s];
        const size_t base = ((size_t)((s0 + s) * BB + b)) * 2048 + d0;
        if (BF) {
            const u16x4 v = *(const u16x4*)((const unsigned short*)encp + base);
            a0 += wg * bf2f(v[0]); a1 += wg * bf2f(v[1]);
            a2 += wg * bf2f(v[2]); a3 += wg * bf2f(v[3]);
        } else {
            const float4 v = *(const float4*)((const float*)encp + base);
            a0 += wg * v.x; a1 += wg * v.y; a2 += wg * v.z; a3 += wg * v.w;
        }
    }
    float4 o; o.x = a0; o.y = a1; o.z = a2; o.w = a3;
    *(float4*)&ctxp[((size_t)sc * BB + b) * 2048 + d0] = o;
}

// ---------------- xcat = bf16(concat(hidden, sum_sc ctxp)) ----------------
__global__ void k_xcat(const float* __restrict__ hidden, const float* __restrict__ ctxp,
                       unsigned short* __restrict__ xcat) {
    const int idx = blockIdx.x * 256 + threadIdx.x;   // 256*768
    const int b = idx / 768, p = idx - b * 768;
    const int e0 = p * 4;
    float4 v;
    if (e0 < 1024) {
        v = *(const float4*)(hidden + (size_t)b * HD + e0);
    } else {
        const int d = e0 - 1024;
        v = *(const float4*)(ctxp + ((size_t)b) * 2048 + d);
#pragma unroll
        for (int sc = 1; sc < 4; ++sc) {
            const float4 u = *(const float4*)(ctxp + ((size_t)sc * BB + b) * 2048 + d);
            v.x += u.x; v.y += u.y; v.z += u.z; v.w += u.w;
        }
    }
    u16x4 o; o[0] = f2bf(v.x); o[1] = f2bf(v.y); o[2] = f2bf(v.z); o[3] = f2bf(v.w);
    *(u16x4*)(xcat + (size_t)b * 3072 + e0) = o;
}

// ---------------- LSTM elementwise (sums 2 split-K gate partials) ----------------
__global__ void k_lstm(const float* __restrict__ gp0, const float* __restrict__ gp1,
                       const float* __restrict__ bih, const float* __restrict__ bhh,
                       const float* __restrict__ cell,
                       float* __restrict__ hout, float* __restrict__ cout,
                       unsigned short* __restrict__ hbf) {
    const int idx = blockIdx.x * 256 + threadIdx.x;  // < 262144
    const int b = idx >> 10, j = idx & 1023;
    const size_t g0 = (size_t)b * 4096;
    const float gi = gp0[g0 + j]        + gp1[g0 + j]        + bih[j]        + bhh[j];
    const float gf = gp0[g0 + 1024 + j] + gp1[g0 + 1024 + j] + bih[1024 + j] + bhh[1024 + j];
    const float gg = gp0[g0 + 2048 + j] + gp1[g0 + 2048 + j] + bih[2048 + j] + bhh[2048 + j];
    const float go = gp0[g0 + 3072 + j] + gp1[g0 + 3072 + j] + bih[3072 + j] + bhh[3072 + j];
    const float c = sigm(gf) * cell[idx] + sigm(gi) * fast_tanh(gg);
    const float h = sigm(go) * fast_tanh(c);
    hout[idx] = h;
    cout[idx] = c;
    hbf[idx] = f2bf(h);
}

// ---------------- log-softmax over VOC (sums 2 split-K logit partials) ----------------
__global__ __launch_bounds__(256) void k_logsoftmax(const float* __restrict__ lp,
                                                    const float* __restrict__ ob,
                                                    float* __restrict__ out) {
    const int b = blockIdx.x, t = threadIdx.x, lane = t & 63, wv = t >> 6;
    __shared__ float red[4];
    const float* r0 = lp + (size_t)b * VOCP;
    const float* r1 = lp + (size_t)BB * VOCP + (size_t)b * VOCP;
    float mx = -3.4e38f;
    for (int j = t; j < VOCN; j += 256) mx = fmaxf(mx, r0[j] + r1[j] + ob[j]);
#pragma unroll
    for (int o = 32; o; o >>= 1) mx = fmaxf(mx, __shfl_xor(mx, o, 64));
    if (lane == 0) red[wv] = mx;
    __syncthreads();
    mx = fmaxf(fmaxf(red[0], red[1]), fmaxf(red[2], red[3]));
    __syncthreads();
    float su = 0.f;
    for (int j = t; j < VOCN; j += 256) su += __expf(r0[j] + r1[j] + ob[j] - mx);
#pragma unroll
    for (int o = 32; o; o >>= 1) su += __shfl_xor(su, o, 64);
    if (lane == 0) red[wv] = su;
    __syncthreads();
    su = red[0] + red[1] + red[2] + red[3];
    const float lse = mx + logf(su);
    for (int j = t; j < VOCN; j += 256) out[(size_t)b * VOCN + j] = r0[j] + r1[j] + ob[j] - lse;
}

// ---------------- launch ----------------
extern "C" void kernel_launch(void* const* d_in, const int* in_sizes, int n_in,
                              void* d_out, int out_size, void* d_ws, size_t ws_size,
                              hipStream_t stream) {
    (void)in_sizes; (void)n_in; (void)out_size;
    const float* hidden = (const float*)d_in[0];
    const float* cell   = (const float*)d_in[1];
    const float* enc    = (const float*)d_in[2];
    const void*  mask   = d_in[3];
    const float* a1w    = (const float*)d_in[4];
    const float* a1b    = (const float*)d_in[5];
    const float* a2w    = (const float*)d_in[6];
    const float* a2b    = (const float*)d_in[7];
    const float* wih    = (const float*)d_in[8];
    const float* whh    = (const float*)d_in[9];
    const float* bih    = (const float*)d_in[10];
    const float* bhh    = (const float*)d_in[11];
    const float* outw   = (const float*)d_in[12];
    const float* outb   = (const float*)d_in[13];

    char* ws = (char*)d_ws;
    unsigned short* w1h   = (unsigned short*)(ws + OFF_W1H);
    unsigned short* w1e   = (unsigned short*)(ws + OFF_W1E);
    unsigned short* wg    = (unsigned short*)(ws + OFF_WG);
    unsigned short* owb   = (unsigned short*)(ws + OFF_OUTW);
    unsigned short* hidbf = (unsigned short*)(ws + OFF_HID);
    unsigned short* xcat  = (unsigned short*)(ws + OFF_XCAT);
    float*          hb    = (float*)(ws + OFF_HB);
    float*          energ = (float*)(ws + OFF_EN);
    float*          gates = (float*)(ws + OFF_GATE);
    unsigned short* hbf   = (unsigned short*)(ws + OFF_HBF);
    float*          logits= (float*)(ws + OFF_LOG);
    unsigned int*   cnt   = (unsigned int*)(ws + OFF_CNT);
    float*          ctxp  = (float*)(ws + OFF_CTX);
    unsigned short* encb  = (unsigned short*)(ws + OFF_ENC);

    float* out  = (float*)d_out;
    float* hout = out + (size_t)BB * VOCN;
    float* cout = hout + (size_t)BB * HD;

    const bool use_enc_bf = ws_size >= NEED_ENC;

    hipMemsetAsync(ws + OFF_CNT, 0, 4, stream);
    k_maskcnt<<<128, 256, 0, stream>>>((const unsigned char*)mask, cnt);
    k_conv_attn1<<<1536, 256, 0, stream>>>(a1w, w1h, w1e);
    k_conv_wg<<<6144, 256, 0, stream>>>(wih, whh, wg);
    k_conv_outw<<<2688, 256, 0, stream>>>(outw, owb);
    k_f2bf<<<128, 256, 0, stream>>>(hidden, hidbf, BB * HD);
    if (use_enc_bf) k_conv_enc<<<32768, 256, 0, stream>>>(enc, encb);

    // hid_proj (raw, bias folded into energy epilogue)  [256,1024]
    k_gemm<0, false, false><<<dim3(16, 1), 256, 0, stream>>>(
        hidbf, w1h, hb, 256, 1024, 1024, 1024, nullptr, nullptr, nullptr, nullptr);
    k_einit<<<128, 256, 0, stream>>>(energ, a2b);
    // enc_proj GEMM with fused tanh/att2/atomic-reduce epilogue
    if (use_enc_bf)
        k_gemm<2, true, false><<<dim3(2048, 1), 256, 0, stream>>>(
            encb, w1e, nullptr, 32768, 1024, 2048, 2048, hb, a1b, a2w, energ);
    else
        k_gemm_f32e<<<2048, 256, 0, stream>>>(enc, w1e, 32768, 1024, 2048, hb, a1b, a2w, energ);
    k_softmax<<<BB, SS, 0, stream>>>(energ, mask, cnt);
    if (use_enc_bf) k_ctx<true><<<dim3(BB, 2, 4), 256, 0, stream>>>(encb, energ, ctxp);
    else            k_ctx<false><<<dim3(BB, 2, 4), 256, 0, stream>>>(enc, energ, ctxp);
    k_xcat<<<768, 256, 0, stream>>>(hidden, ctxp, xcat);
    // gates = xcat @ wg^T  [256,4096], split-K=2 partials
    k_gemm<0, false, true><<<dim3(64, 2), 256, 0, stream>>>(
        xcat, wg, gates, 256, 4096, 3072, 1536, nullptr, nullptr, nullptr, nullptr);
    k_lstm<<<1024, 256, 0, stream>>>(gates, gates + (size_t)BB * 4096, bih, bhh, cell,
                                     hout, cout, hbf);
    // logits = h_new @ out_w^T  [256,5376(pad)], split-K=2 partials
    k_gemm<0, false, true><<<dim3(84, 2), 256, 0, stream>>>(
        hbf, owb, logits, 256, VOCP, 1024, 512, nullptr, nullptr, nullptr, nullptr);
    k_logsoftmax<<<BB, 256, 0, stream>>>(logits, outb, out);
}